// Round 6
// baseline (264.725 us; speedup 1.0000x reference)
//
#include <hip/hip_runtime.h>
#include <hip/hip_bf16.h>
#include <stdint.h>

#define BDIM 2048
#define HDIM 1024
#define XDIM 1024
#define BH (BDIM*HDIM)
#define WSEG 1048576  // 1M elements per segment

typedef __attribute__((ext_vector_type(8))) short short8;
typedef __attribute__((ext_vector_type(4))) float float4v;

__device__ __forceinline__ void gload16(const void* g, void* l) {
    __builtin_amdgcn_global_load_lds(
        (const __attribute__((address_space(1))) unsigned int*)g,
        (__attribute__((address_space(3))) unsigned int*)l, 16, 0, 0);
}

__device__ __forceinline__ unsigned pack2(float a, float b) {
    __hip_bfloat162 v = __float22bfloat162_rn(make_float2(a, b));
    return *reinterpret_cast<unsigned*>(&v);
}
__device__ __forceinline__ uint2 pack4(float4 f) {
    return make_uint2(pack2(f.x, f.y), pack2(f.z, f.w));
}
__device__ __forceinline__ float2 up2(unsigned u) {
    __hip_bfloat162 v = *reinterpret_cast<__hip_bfloat162*>(&u);
    return __bfloat1622float2(v);
}

// ---------------- prep_w: fp32 -> bf16 for the 8 weight matrices only ----------------
// ws bf16 segment map (1M elems each): segs 0..3 = wx[i,f,c,o], segs 4..7 = wh[i,f,c,o]
__global__ __launch_bounds__(256) void prep_w_k(
    const float* __restrict__ w0, const float* __restrict__ w1,
    const float* __restrict__ w2, const float* __restrict__ w3,
    const float* __restrict__ w4, const float* __restrict__ w5,
    const float* __restrict__ w6, const float* __restrict__ w7,
    uint2* __restrict__ dst) {
    const int seg = blockIdx.y;
    const int i = blockIdx.x * 256 + threadIdx.x;   // float4 index within segment (262144)
    const float* base;
    switch (seg) {
        case 0: base = w0; break; case 1: base = w1; break;
        case 2: base = w2; break; case 3: base = w3; break;
        case 4: base = w4; break; case 5: base = w5; break;
        case 6: base = w6; break; default: base = w7; break;
    }
    float4 f = ((const float4*)base)[i];
    dst[(size_t)seg * (WSEG / 4) + i] = pack4(f);
}

// ---------------- gemm split-K, fused A-side conversion ----------------
// z=2g+half: half=0 -> A=x (fp32), B=wx_g ; half=1 -> A=h0*maskHg (fp32, fused), B=wh_g.
// part[z][b][n] = A[b,:]·B[n,:]  (bf16 out).  K=1024 per block.
// 128x128 tile, BK=32, 256 threads (4 waves 2x2), 4x4 of 16x16x32 bf16 MFMA.
// B staged via async global_load_lds (bf16 ws); A staged via VGPR fp32 load + cvt + ds_write_b128.
__global__ __launch_bounds__(256, 4) void gemm_split(
    const __hip_bfloat16* __restrict__ wsw,   // 8 x 1M bf16 weights
    const float* __restrict__ x, const float* __restrict__ h0,
    const float* __restrict__ mI, const float* __restrict__ mF,
    const float* __restrict__ mC, const float* __restrict__ mO,
    __hip_bfloat16* __restrict__ part) {      // 8 x BH bf16
    const int z = blockIdx.z;
    const int g = z >> 1, half = z & 1;
    const float* Afp = half ? h0 : x;
    const float* Mfp = (g == 0) ? mI : (g == 1) ? mF : (g == 2) ? mC : mO;
    const __hip_bfloat16* Bp = wsw + (size_t)(half ? (4 + g) : g) * WSEG;

    __shared__ __hip_bfloat16 As[128 * 32];
    __shared__ __hip_bfloat16 Bs[128 * 32];

    const int t = threadIdx.x;
    const int m0 = blockIdx.x * 128;
    const int n0 = blockIdx.y * 128;
    const int wv = t >> 6, lane = t & 63;
    const int wm = (wv >> 1) * 64, wn = (wv & 1) * 64;
    const int quad = lane >> 4, lrow = lane & 15;

    float4v acc[4][4];
#pragma unroll
    for (int i = 0; i < 4; ++i)
#pragma unroll
        for (int j = 0; j < 4; ++j) acc[i][j] = (float4v){0.f, 0.f, 0.f, 0.f};

    const short8* As8 = (const short8*)As;
    const short8* Bs8 = (const short8*)Bs;
    uint4* As16 = (uint4*)As;

    for (int k0 = 0; k0 < 1024; k0 += 32) {
        // B: async bf16 staging (2 chunks of 16B per thread)
#pragma unroll
        for (int it = 0; it < 2; ++it) {
            int chunk = it * 256 + t;
            int row = chunk >> 2, cc = chunk & 3;
            gload16(Bp + (size_t)(n0 + row) * 1024 + k0 + cc * 8,
                    (char*)Bs + chunk * 16);
        }
        // A: fp32 load (+mask mul) + cvt + ds_write_b128 (2 chunks of 8 elems per thread)
#pragma unroll
        for (int it = 0; it < 2; ++it) {
            int chunk = it * 256 + t;
            int row = chunk >> 2, cc = chunk & 3;
            size_t off = (size_t)(m0 + row) * 1024 + k0 + cc * 8;
            float4 a0 = *(const float4*)(Afp + off);
            float4 a1 = *(const float4*)(Afp + off + 4);
            if (half) {
                float4 q0 = *(const float4*)(Mfp + off);
                float4 q1 = *(const float4*)(Mfp + off + 4);
                a0 = make_float4(a0.x * q0.x, a0.y * q0.y, a0.z * q0.z, a0.w * q0.w);
                a1 = make_float4(a1.x * q1.x, a1.y * q1.y, a1.z * q1.z, a1.w * q1.w);
            }
            As16[chunk] = make_uint4(pack2(a0.x, a0.y), pack2(a0.z, a0.w),
                                     pack2(a1.x, a1.y), pack2(a1.z, a1.w));
        }
        __syncthreads();

        short8 af[4], bfr[4];
#pragma unroll
        for (int mt = 0; mt < 4; ++mt) af[mt] = As8[(wm + mt * 16 + lrow) * 4 + quad];
#pragma unroll
        for (int nt = 0; nt < 4; ++nt) bfr[nt] = Bs8[(wn + nt * 16 + lrow) * 4 + quad];
#pragma unroll
        for (int mt = 0; mt < 4; ++mt)
#pragma unroll
            for (int nt = 0; nt < 4; ++nt)
                acc[mt][nt] = __builtin_amdgcn_mfma_f32_16x16x32_bf16(
                    af[mt], bfr[nt], acc[mt][nt], 0, 0, 0);
        __syncthreads();
    }

    // epilogue: C/D layout col=lane&15, row=quad*4+r (m89/m91 verified); bf16 partial
    __hip_bfloat16* pz = part + (size_t)z * BH;
#pragma unroll
    for (int nt = 0; nt < 4; ++nt) {
        int col = n0 + wn + nt * 16 + lrow;
#pragma unroll
        for (int mt = 0; mt < 4; ++mt) {
#pragma unroll
            for (int r = 0; r < 4; ++r) {
                int row = m0 + wm + mt * 16 + quad * 4 + r;
                pz[(size_t)row * HDIM + col] = __float2bfloat16(acc[mt][nt][r]);
            }
        }
    }
}

// ---------------- combine: sum split-K partials + bias -> gates -> h1, c1 (fp32 out) ----------------
__global__ __launch_bounds__(256) void combine_k(
    const uint2* __restrict__ part,   // 8 x BH bf16, as uint2 = 4 elems
    const float* __restrict__ bi, const float* __restrict__ bff,
    const float* __restrict__ bc, const float* __restrict__ bo,
    const float* __restrict__ c0, const float* __restrict__ mC,
    float4* __restrict__ out) {
    const int i = blockIdx.x * 256 + threadIdx.x;   // 4-elem group index over BH/4
    const int h4 = (i * 4 & (HDIM - 1)) >> 2;       // float4 index into biases

    float gate[4][4];
#pragma unroll
    for (int g = 0; g < 4; ++g) {
        uint2 p0 = part[(size_t)(2 * g) * (BH / 4) + i];
        uint2 p1 = part[(size_t)(2 * g + 1) * (BH / 4) + i];
        float2 a0 = up2(p0.x), a1 = up2(p0.y);
        float2 b0 = up2(p1.x), b1 = up2(p1.y);
        gate[g][0] = a0.x + b0.x;
        gate[g][1] = a0.y + b0.y;
        gate[g][2] = a1.x + b1.x;
        gate[g][3] = a1.y + b1.y;
    }
    float4 vbi = ((const float4*)bi)[h4];
    float4 vbf = ((const float4*)bff)[h4];
    float4 vbc = ((const float4*)bc)[h4];
    float4 vbo = ((const float4*)bo)[h4];
    float4 vc0 = ((const float4*)c0)[i];
    float4 vmc = ((const float4*)mC)[i];
    const float* pbi = (const float*)&vbi;
    const float* pbf = (const float*)&vbf;
    const float* pbc = (const float*)&vbc;
    const float* pbo = (const float*)&vbo;
    const float* pc0 = (const float*)&vc0;
    const float* pmc = (const float*)&vmc;

    float h1[4], c1[4];
#pragma unroll
    for (int j = 0; j < 4; ++j) {
        float xi = gate[0][j] + pbi[j];
        float xf = gate[1][j] + pbf[j];
        float xc = gate[2][j] + pbc[j];
        float xo = gate[3][j] + pbo[j];
        float I = 1.f / (1.f + __expf(-xi));
        float F = 1.f / (1.f + __expf(-xf));
        float C = tanhf(xc) * pmc[j];
        float O = 1.f / (1.f + __expf(-xo));
        c1[j] = F * pc0[j] + I * C;
        h1[j] = O * tanhf(c1[j]);
    }
    out[i] = make_float4(h1[0], h1[1], h1[2], h1[3]);
    out[BH / 4 + i] = make_float4(c1[0], c1[1], c1[2], c1[3]);
}

extern "C" void kernel_launch(void* const* d_in, const int* in_sizes, int n_in,
                              void* d_out, int out_size, void* d_ws, size_t ws_size,
                              hipStream_t stream) {
    const float* x   = (const float*)d_in[0];
    const float* h0  = (const float*)d_in[1];
    const float* c0  = (const float*)d_in[2];
    const float* wxi = (const float*)d_in[3];
    const float* wxf = (const float*)d_in[4];
    const float* wxc = (const float*)d_in[5];
    const float* wxo = (const float*)d_in[6];
    const float* whi = (const float*)d_in[7];
    const float* whf = (const float*)d_in[8];
    const float* whc = (const float*)d_in[9];
    const float* who = (const float*)d_in[10];
    const float* bi  = (const float*)d_in[11];
    const float* bf  = (const float*)d_in[12];
    const float* bc  = (const float*)d_in[13];
    const float* bo  = (const float*)d_in[14];
    const float* mI  = (const float*)d_in[15];
    const float* mF  = (const float*)d_in[16];
    const float* mC  = (const float*)d_in[17];
    const float* mO  = (const float*)d_in[18];
    const float* mCell = (const float*)d_in[19];

    // ws layout: weights 8*1M bf16 = 16 MB | part: 8*BH bf16 = 32 MB
    __hip_bfloat16* wsw = (__hip_bfloat16*)d_ws;
    __hip_bfloat16* part = wsw + (size_t)8 * WSEG;

    prep_w_k<<<dim3(WSEG / 4 / 256, 8), dim3(256), 0, stream>>>(
        wxi, wxf, wxc, wxo, whi, whf, whc, who, (uint2*)wsw);

    gemm_split<<<dim3(BDIM / 128, HDIM / 128, 8), dim3(256), 0, stream>>>(
        wsw, x, h0, mI, mF, mC, mO, part);

    combine_k<<<dim3(BH / 4 / 256), dim3(256), 0, stream>>>(
        (const uint2*)part, bi, bf, bc, bo, c0, mCell, (float4*)d_out);
}

// Round 7
// 210.796 us; speedup vs baseline: 1.2558x; 1.2558x over previous
//
#include <hip/hip_runtime.h>
#include <hip/hip_bf16.h>
#include <stdint.h>

#define BDIM 2048
#define HDIM 1024
#define XDIM 1024
#define BH (BDIM*HDIM)
#define WSEG 1048576  // 1M elements per segment

typedef __attribute__((ext_vector_type(8))) short short8;
typedef __attribute__((ext_vector_type(4))) float float4v;

__device__ __forceinline__ void gload16(const void* g, void* l) {
    __builtin_amdgcn_global_load_lds(
        (const __attribute__((address_space(1))) unsigned int*)g,
        (__attribute__((address_space(3))) unsigned int*)l, 16, 0, 0);
}

__device__ __forceinline__ unsigned pack2(float a, float b) {
    __hip_bfloat162 v = __float22bfloat162_rn(make_float2(a, b));
    return *reinterpret_cast<unsigned*>(&v);
}
__device__ __forceinline__ uint2 pack4(float4 f) {
    return make_uint2(pack2(f.x, f.y), pack2(f.z, f.w));
}
__device__ __forceinline__ float2 up2(unsigned u) {
    __hip_bfloat162 v = *reinterpret_cast<__hip_bfloat162*>(&u);
    return __bfloat1622float2(v);
}

// ---------------- prep_all: fp32 -> bf16 for everything the GEMM eats ----------------
// ws bf16 segment map (1M elems each):
//   segs 0..7  : wxi,wxf,wxc,wxo,whi,whf,whc,who
//   segs 8..9  : x (rows 0..1023, 1024..2047)
//   segs 10..17: hm[g][rowhalf] = h0 * maskHg   (hm_g contiguous as 2048x1024)
__global__ __launch_bounds__(256) void prep_all_k(
    const float* __restrict__ w0, const float* __restrict__ w1,
    const float* __restrict__ w2, const float* __restrict__ w3,
    const float* __restrict__ w4, const float* __restrict__ w5,
    const float* __restrict__ w6, const float* __restrict__ w7,
    const float* __restrict__ x, const float* __restrict__ h0,
    const float* __restrict__ mI, const float* __restrict__ mF,
    const float* __restrict__ mC, const float* __restrict__ mO,
    uint2* __restrict__ dst) {
    const int seg = blockIdx.y;
    const int i = blockIdx.x * 256 + threadIdx.x;   // float4 index within segment (262144)
    float4 f;
    if (seg < 10) {
        const float* base;
        switch (seg) {
            case 0: base = w0; break; case 1: base = w1; break;
            case 2: base = w2; break; case 3: base = w3; break;
            case 4: base = w4; break; case 5: base = w5; break;
            case 6: base = w6; break; case 7: base = w7; break;
            default: base = x + (size_t)(seg - 8) * WSEG; break;
        }
        f = ((const float4*)base)[i];
    } else {
        const int s = seg - 10;
        const int g = s >> 1, half = s & 1;
        const float* mp = (g == 0) ? mI : (g == 1) ? mF : (g == 2) ? mC : mO;
        float4 h = ((const float4*)(h0 + (size_t)half * WSEG))[i];
        float4 m = ((const float4*)(mp + (size_t)half * WSEG))[i];
        f = make_float4(h.x * m.x, h.y * m.y, h.z * m.z, h.w * m.w);
    }
    dst[(size_t)seg * (WSEG / 4) + i] = pack4(f);
}

// ---------------- gemm split-K: part[z=2g+half][b][n] = A_half[b,:]·B_gh[n,:]  (bf16 out) ----------------
// z=2g+half: half=0 -> A=x, B=wx_g ; half=1 -> A=hm_g, B=wh_g.  K=1024 per block.
// 128x128 tile, BK=64 (32 MFMA per barrier), 256 threads (4 waves 2x2),
// 4x4 of 16x16x32 bf16 MFMA per wave, 2 k-steps per tile.
__global__ __launch_bounds__(256, 4) void gemm_split(
    const __hip_bfloat16* __restrict__ ws18,  // 18 x 1M bf16 per prep_all map
    __hip_bfloat16* __restrict__ part) {      // 8 x BH bf16
    const int z = blockIdx.z;
    const int g = z >> 1, half = z & 1;
    const __hip_bfloat16* Ap = half ? (ws18 + (size_t)(10 + 2 * g) * WSEG)
                                    : (ws18 + (size_t)8 * WSEG);
    const __hip_bfloat16* Bp = half ? (ws18 + (size_t)(4 + g) * WSEG)
                                    : (ws18 + (size_t)g * WSEG);

    __shared__ __hip_bfloat16 As[128 * 64];
    __shared__ __hip_bfloat16 Bs[128 * 64];

    const int t = threadIdx.x;
    const int m0 = blockIdx.x * 128;
    const int n0 = blockIdx.y * 128;
    const int wv = t >> 6, lane = t & 63;
    const int wm = (wv >> 1) * 64, wn = (wv & 1) * 64;
    const int quad = lane >> 4, lrow = lane & 15;

    float4v acc[4][4];
#pragma unroll
    for (int i = 0; i < 4; ++i)
#pragma unroll
        for (int j = 0; j < 4; ++j) acc[i][j] = (float4v){0.f, 0.f, 0.f, 0.f};

    const short8* As8 = (const short8*)As;
    const short8* Bs8 = (const short8*)Bs;

    for (int k0 = 0; k0 < 1024; k0 += 64) {
        // stage A-tile and B-tile (128 rows x 64 k): 1024 chunks of 16B each per matrix,
        // 256 threads x 4 chunks.  row = chunk>>3 (8 chunks/row), cc = chunk&7.
#pragma unroll
        for (int it = 0; it < 4; ++it) {
            int chunk = it * 256 + t;
            int row = chunk >> 3, cc = chunk & 7;
            gload16(Ap + (size_t)(m0 + row) * 1024 + k0 + cc * 8,
                    (char*)As + chunk * 16);
            gload16(Bp + (size_t)(n0 + row) * 1024 + k0 + cc * 8,
                    (char*)Bs + chunk * 16);
        }
        __syncthreads();

        // 2 k-steps of 32: row stride = 8 short8; within row, ks*4 + quad
#pragma unroll
        for (int ks = 0; ks < 2; ++ks) {
            short8 af[4], bfr[4];
#pragma unroll
            for (int mt = 0; mt < 4; ++mt)
                af[mt] = As8[(wm + mt * 16 + lrow) * 8 + ks * 4 + quad];
#pragma unroll
            for (int nt = 0; nt < 4; ++nt)
                bfr[nt] = Bs8[(wn + nt * 16 + lrow) * 8 + ks * 4 + quad];
#pragma unroll
            for (int mt = 0; mt < 4; ++mt)
#pragma unroll
                for (int nt = 0; nt < 4; ++nt)
                    acc[mt][nt] = __builtin_amdgcn_mfma_f32_16x16x32_bf16(
                        af[mt], bfr[nt], acc[mt][nt], 0, 0, 0);
        }
        __syncthreads();
    }

    // epilogue: C/D layout col=lane&15, row=quad*4+r (m89/m91 verified); bf16 partial
    __hip_bfloat16* pz = part + (size_t)z * BH;
#pragma unroll
    for (int nt = 0; nt < 4; ++nt) {
        int col = n0 + wn + nt * 16 + lrow;
#pragma unroll
        for (int mt = 0; mt < 4; ++mt) {
#pragma unroll
            for (int r = 0; r < 4; ++r) {
                int row = m0 + wm + mt * 16 + quad * 4 + r;
                pz[(size_t)row * HDIM + col] = __float2bfloat16(acc[mt][nt][r]);
            }
        }
    }
}

// ---------------- combine: sum split-K partials + bias -> gates -> h1, c1 (fp32 out) ----------------
__global__ __launch_bounds__(256) void combine_k(
    const uint2* __restrict__ part,   // 8 x BH bf16, as uint2 = 4 elems
    const float* __restrict__ bi, const float* __restrict__ bff,
    const float* __restrict__ bc, const float* __restrict__ bo,
    const float* __restrict__ c0, const float* __restrict__ mC,
    float4* __restrict__ out) {
    const int i = blockIdx.x * 256 + threadIdx.x;   // 4-elem group index over BH/4
    const int h4 = (i * 4 & (HDIM - 1)) >> 2;       // float4 index into biases

    float gate[4][4];
#pragma unroll
    for (int g = 0; g < 4; ++g) {
        uint2 p0 = part[(size_t)(2 * g) * (BH / 4) + i];
        uint2 p1 = part[(size_t)(2 * g + 1) * (BH / 4) + i];
        float2 a0 = up2(p0.x), a1 = up2(p0.y);
        float2 b0 = up2(p1.x), b1 = up2(p1.y);
        gate[g][0] = a0.x + b0.x;
        gate[g][1] = a0.y + b0.y;
        gate[g][2] = a1.x + b1.x;
        gate[g][3] = a1.y + b1.y;
    }
    float4 vbi = ((const float4*)bi)[h4];
    float4 vbf = ((const float4*)bff)[h4];
    float4 vbc = ((const float4*)bc)[h4];
    float4 vbo = ((const float4*)bo)[h4];
    float4 vc0 = ((const float4*)c0)[i];
    float4 vmc = ((const float4*)mC)[i];
    const float* pbi = (const float*)&vbi;
    const float* pbf = (const float*)&vbf;
    const float* pbc = (const float*)&vbc;
    const float* pbo = (const float*)&vbo;
    const float* pc0 = (const float*)&vc0;
    const float* pmc = (const float*)&vmc;

    float h1[4], c1[4];
#pragma unroll
    for (int j = 0; j < 4; ++j) {
        float xi = gate[0][j] + pbi[j];
        float xf = gate[1][j] + pbf[j];
        float xc = gate[2][j] + pbc[j];
        float xo = gate[3][j] + pbo[j];
        float I = 1.f / (1.f + __expf(-xi));
        float F = 1.f / (1.f + __expf(-xf));
        float C = tanhf(xc) * pmc[j];
        float O = 1.f / (1.f + __expf(-xo));
        c1[j] = F * pc0[j] + I * C;
        h1[j] = O * tanhf(c1[j]);
    }
    out[i] = make_float4(h1[0], h1[1], h1[2], h1[3]);
    out[BH / 4 + i] = make_float4(c1[0], c1[1], c1[2], c1[3]);
}

extern "C" void kernel_launch(void* const* d_in, const int* in_sizes, int n_in,
                              void* d_out, int out_size, void* d_ws, size_t ws_size,
                              hipStream_t stream) {
    const float* x   = (const float*)d_in[0];
    const float* h0  = (const float*)d_in[1];
    const float* c0  = (const float*)d_in[2];
    const float* wxi = (const float*)d_in[3];
    const float* wxf = (const float*)d_in[4];
    const float* wxc = (const float*)d_in[5];
    const float* wxo = (const float*)d_in[6];
    const float* whi = (const float*)d_in[7];
    const float* whf = (const float*)d_in[8];
    const float* whc = (const float*)d_in[9];
    const float* who = (const float*)d_in[10];
    const float* bi  = (const float*)d_in[11];
    const float* bf  = (const float*)d_in[12];
    const float* bc  = (const float*)d_in[13];
    const float* bo  = (const float*)d_in[14];
    const float* mI  = (const float*)d_in[15];
    const float* mF  = (const float*)d_in[16];
    const float* mC  = (const float*)d_in[17];
    const float* mO  = (const float*)d_in[18];
    const float* mCell = (const float*)d_in[19];

    // ws layout: 18*1M bf16 = 36 MB | part: 8*BH bf16 = 32 MB
    __hip_bfloat16* ws18 = (__hip_bfloat16*)d_ws;
    __hip_bfloat16* part = ws18 + (size_t)18 * WSEG;

    prep_all_k<<<dim3(WSEG / 4 / 256, 18), dim3(256), 0, stream>>>(
        wxi, wxf, wxc, wxo, whi, whf, whc, who, x, h0, mI, mF, mC, mO,
        (uint2*)ws18);

    gemm_split<<<dim3(BDIM / 128, HDIM / 128, 8), dim3(256), 0, stream>>>(
        ws18, part);

    combine_k<<<dim3(BH / 4 / 256), dim3(256), 0, stream>>>(
        (const uint2*)part, bi, bf, bc, bo, c0, mCell, (float4*)d_out);
}

// Round 8
// 210.590 us; speedup vs baseline: 1.2571x; 1.0010x over previous
//
#include <hip/hip_runtime.h>
#include <hip/hip_bf16.h>
#include <stdint.h>

#define BDIM 2048
#define HDIM 1024
#define XDIM 1024
#define BH (BDIM*HDIM)
#define WSEG 1048576  // 1M elements per segment

typedef __attribute__((ext_vector_type(8))) short short8;
typedef __attribute__((ext_vector_type(4))) float float4v;

__device__ __forceinline__ void gload16(const void* g, void* l) {
    __builtin_amdgcn_global_load_lds(
        (const __attribute__((address_space(1))) unsigned int*)g,
        (__attribute__((address_space(3))) unsigned int*)l, 16, 0, 0);
}

__device__ __forceinline__ unsigned pack2(float a, float b) {
    __hip_bfloat162 v = __float22bfloat162_rn(make_float2(a, b));
    return *reinterpret_cast<unsigned*>(&v);
}
__device__ __forceinline__ uint2 pack4(float4 f) {
    return make_uint2(pack2(f.x, f.y), pack2(f.z, f.w));
}
__device__ __forceinline__ float2 up2(unsigned u) {
    __hip_bfloat162 v = *reinterpret_cast<__hip_bfloat162*>(&u);
    return __bfloat1622float2(v);
}

// ---------------- prep_all: fp32 -> bf16 for everything the GEMM eats ----------------
// ws bf16 segment map (1M elems each):
//   segs 0..7  : wxi,wxf,wxc,wxo,whi,whf,whc,who
//   segs 8..9  : x (rows 0..1023, 1024..2047)
//   segs 10..17: hm[g][rowhalf] = h0 * maskHg   (hm_g contiguous as 2048x1024)
__global__ __launch_bounds__(256) void prep_all_k(
    const float* __restrict__ w0, const float* __restrict__ w1,
    const float* __restrict__ w2, const float* __restrict__ w3,
    const float* __restrict__ w4, const float* __restrict__ w5,
    const float* __restrict__ w6, const float* __restrict__ w7,
    const float* __restrict__ x, const float* __restrict__ h0,
    const float* __restrict__ mI, const float* __restrict__ mF,
    const float* __restrict__ mC, const float* __restrict__ mO,
    uint2* __restrict__ dst) {
    const int seg = blockIdx.y;
    const int i = blockIdx.x * 256 + threadIdx.x;   // float4 index within segment (262144)
    float4 f;
    if (seg < 10) {
        const float* base;
        switch (seg) {
            case 0: base = w0; break; case 1: base = w1; break;
            case 2: base = w2; break; case 3: base = w3; break;
            case 4: base = w4; break; case 5: base = w5; break;
            case 6: base = w6; break; case 7: base = w7; break;
            default: base = x + (size_t)(seg - 8) * WSEG; break;
        }
        f = ((const float4*)base)[i];
    } else {
        const int s = seg - 10;
        const int g = s >> 1, half = s & 1;
        const float* mp = (g == 0) ? mI : (g == 1) ? mF : (g == 2) ? mC : mO;
        float4 h = ((const float4*)(h0 + (size_t)half * WSEG))[i];
        float4 m = ((const float4*)(mp + (size_t)half * WSEG))[i];
        f = make_float4(h.x * m.x, h.y * m.y, h.z * m.z, h.w * m.w);
    }
    dst[(size_t)seg * (WSEG / 4) + i] = pack4(f);
}

// ---------------- gemm split-K: part[z=2g+half][b][n] = A_half[b,:]·B_gh[n,:]  (bf16 out) ----------------
// z=2g+half: half=0 -> A=x, B=wx_g ; half=1 -> A=hm_g, B=wh_g.  K=1024 per block.
// 128x128 tile, BK=64 (32 MFMA per barrier), 256 threads (4 waves 2x2),
// 4x4 of 16x16x32 bf16 MFMA per wave, 2 k-steps per tile.
// LDS layout XOR-swizzled: 16B chunk c holds row=c>>3, col-group (c&7)^(row&7).
// Staged via global_load_lds by swizzling the SOURCE address (dest must stay
// lane-contiguous); fragment reads land 8 distinct bank-quads -> 2 lanes/bank (free).
__global__ __launch_bounds__(256, 4) void gemm_split(
    const __hip_bfloat16* __restrict__ ws18,  // 18 x 1M bf16 per prep_all map
    __hip_bfloat16* __restrict__ part) {      // 8 x BH bf16
    const int z = blockIdx.z;
    const int g = z >> 1, half = z & 1;
    const __hip_bfloat16* Ap = half ? (ws18 + (size_t)(10 + 2 * g) * WSEG)
                                    : (ws18 + (size_t)8 * WSEG);
    const __hip_bfloat16* Bp = half ? (ws18 + (size_t)(4 + g) * WSEG)
                                    : (ws18 + (size_t)g * WSEG);

    __shared__ __hip_bfloat16 As[128 * 64];
    __shared__ __hip_bfloat16 Bs[128 * 64];

    const int t = threadIdx.x;
    const int m0 = blockIdx.x * 128;
    const int n0 = blockIdx.y * 128;
    const int wv = t >> 6, lane = t & 63;
    const int wm = (wv >> 1) * 64, wn = (wv & 1) * 64;
    const int quad = lane >> 4, lrow = lane & 15;

    float4v acc[4][4];
#pragma unroll
    for (int i = 0; i < 4; ++i)
#pragma unroll
        for (int j = 0; j < 4; ++j) acc[i][j] = (float4v){0.f, 0.f, 0.f, 0.f};

    const short8* As8 = (const short8*)As;
    const short8* Bs8 = (const short8*)Bs;

    for (int k0 = 0; k0 < 1024; k0 += 64) {
        // stage A-tile and B-tile (128 rows x 64 k): 1024 chunks of 16B per matrix,
        // 256 threads x 4.  chunk -> row = chunk>>3, SRC col-group = (chunk&7)^(row&7).
#pragma unroll
        for (int it = 0; it < 4; ++it) {
            int chunk = it * 256 + t;
            int row = chunk >> 3;
            int ccs = (chunk & 7) ^ (row & 7);
            gload16(Ap + (size_t)(m0 + row) * 1024 + k0 + ccs * 8,
                    (char*)As + chunk * 16);
            gload16(Bp + (size_t)(n0 + row) * 1024 + k0 + ccs * 8,
                    (char*)Bs + chunk * 16);
        }
        __syncthreads();

        // 2 k-steps of 32: logical col-chunk q = ks*4+quad lives at row*8 + (q^(row&7))
#pragma unroll
        for (int ks = 0; ks < 2; ++ks) {
            short8 af[4], bfr[4];
#pragma unroll
            for (int mt = 0; mt < 4; ++mt) {
                int r = wm + mt * 16 + lrow;
                af[mt] = As8[(r << 3) + ((ks * 4 + quad) ^ (r & 7))];
            }
#pragma unroll
            for (int nt = 0; nt < 4; ++nt) {
                int r = wn + nt * 16 + lrow;
                bfr[nt] = Bs8[(r << 3) + ((ks * 4 + quad) ^ (r & 7))];
            }
#pragma unroll
            for (int mt = 0; mt < 4; ++mt)
#pragma unroll
                for (int nt = 0; nt < 4; ++nt)
                    acc[mt][nt] = __builtin_amdgcn_mfma_f32_16x16x32_bf16(
                        af[mt], bfr[nt], acc[mt][nt], 0, 0, 0);
        }
        __syncthreads();
    }

    // epilogue: C/D layout col=lane&15, row=quad*4+r (m89/m91 verified); bf16 partial
    __hip_bfloat16* pz = part + (size_t)z * BH;
#pragma unroll
    for (int nt = 0; nt < 4; ++nt) {
        int col = n0 + wn + nt * 16 + lrow;
#pragma unroll
        for (int mt = 0; mt < 4; ++mt) {
#pragma unroll
            for (int r = 0; r < 4; ++r) {
                int row = m0 + wm + mt * 16 + quad * 4 + r;
                pz[(size_t)row * HDIM + col] = __float2bfloat16(acc[mt][nt][r]);
            }
        }
    }
}

// ---------------- combine: sum split-K partials + bias -> gates -> h1, c1 (fp32 out) ----------------
__global__ __launch_bounds__(256) void combine_k(
    const uint2* __restrict__ part,   // 8 x BH bf16, as uint2 = 4 elems
    const float* __restrict__ bi, const float* __restrict__ bff,
    const float* __restrict__ bc, const float* __restrict__ bo,
    const float* __restrict__ c0, const float* __restrict__ mC,
    float4* __restrict__ out) {
    const int i = blockIdx.x * 256 + threadIdx.x;   // 4-elem group index over BH/4
    const int h4 = (i * 4 & (HDIM - 1)) >> 2;       // float4 index into biases

    float gate[4][4];
#pragma unroll
    for (int g = 0; g < 4; ++g) {
        uint2 p0 = part[(size_t)(2 * g) * (BH / 4) + i];
        uint2 p1 = part[(size_t)(2 * g + 1) * (BH / 4) + i];
        float2 a0 = up2(p0.x), a1 = up2(p0.y);
        float2 b0 = up2(p1.x), b1 = up2(p1.y);
        gate[g][0] = a0.x + b0.x;
        gate[g][1] = a0.y + b0.y;
        gate[g][2] = a1.x + b1.x;
        gate[g][3] = a1.y + b1.y;
    }
    float4 vbi = ((const float4*)bi)[h4];
    float4 vbf = ((const float4*)bff)[h4];
    float4 vbc = ((const float4*)bc)[h4];
    float4 vbo = ((const float4*)bo)[h4];
    float4 vc0 = ((const float4*)c0)[i];
    float4 vmc = ((const float4*)mC)[i];
    const float* pbi = (const float*)&vbi;
    const float* pbf = (const float*)&vbf;
    const float* pbc = (const float*)&vbc;
    const float* pbo = (const float*)&vbo;
    const float* pc0 = (const float*)&vc0;
    const float* pmc = (const float*)&vmc;

    float h1[4], c1[4];
#pragma unroll
    for (int j = 0; j < 4; ++j) {
        float xi = gate[0][j] + pbi[j];
        float xf = gate[1][j] + pbf[j];
        float xc = gate[2][j] + pbc[j];
        float xo = gate[3][j] + pbo[j];
        float I = 1.f / (1.f + __expf(-xi));
        float F = 1.f / (1.f + __expf(-xf));
        float C = tanhf(xc) * pmc[j];
        float O = 1.f / (1.f + __expf(-xo));
        c1[j] = F * pc0[j] + I * C;
        h1[j] = O * tanhf(c1[j]);
    }
    out[i] = make_float4(h1[0], h1[1], h1[2], h1[3]);
    out[BH / 4 + i] = make_float4(c1[0], c1[1], c1[2], c1[3]);
}

extern "C" void kernel_launch(void* const* d_in, const int* in_sizes, int n_in,
                              void* d_out, int out_size, void* d_ws, size_t ws_size,
                              hipStream_t stream) {
    const float* x   = (const float*)d_in[0];
    const float* h0  = (const float*)d_in[1];
    const float* c0  = (const float*)d_in[2];
    const float* wxi = (const float*)d_in[3];
    const float* wxf = (const float*)d_in[4];
    const float* wxc = (const float*)d_in[5];
    const float* wxo = (const float*)d_in[6];
    const float* whi = (const float*)d_in[7];
    const float* whf = (const float*)d_in[8];
    const float* whc = (const float*)d_in[9];
    const float* who = (const float*)d_in[10];
    const float* bi  = (const float*)d_in[11];
    const float* bf  = (const float*)d_in[12];
    const float* bc  = (const float*)d_in[13];
    const float* bo  = (const float*)d_in[14];
    const float* mI  = (const float*)d_in[15];
    const float* mF  = (const float*)d_in[16];
    const float* mC  = (const float*)d_in[17];
    const float* mO  = (const float*)d_in[18];
    const float* mCell = (const float*)d_in[19];

    // ws layout: 18*1M bf16 = 36 MB | part: 8*BH bf16 = 32 MB
    __hip_bfloat16* ws18 = (__hip_bfloat16*)d_ws;
    __hip_bfloat16* part = ws18 + (size_t)18 * WSEG;

    prep_all_k<<<dim3(WSEG / 4 / 256, 18), dim3(256), 0, stream>>>(
        wxi, wxf, wxc, wxo, whi, whf, whc, who, x, h0, mI, mF, mC, mO,
        (uint2*)ws18);

    gemm_split<<<dim3(BDIM / 128, HDIM / 128, 8), dim3(256), 0, stream>>>(
        ws18, part);

    combine_k<<<dim3(BH / 4 / 256), dim3(256), 0, stream>>>(
        (const uint2*)part, bi, bf, bc, bo, c0, mCell, (float4*)d_out);
}

// Round 9
// 205.410 us; speedup vs baseline: 1.2888x; 1.0252x over previous
//
#include <hip/hip_runtime.h>
#include <hip/hip_bf16.h>
#include <stdint.h>

#define BDIM 2048
#define HDIM 1024
#define XDIM 1024
#define BH (BDIM*HDIM)
#define WSEG 1048576  // 1M elements per segment

typedef __attribute__((ext_vector_type(8))) short short8;
typedef __attribute__((ext_vector_type(4))) float float4v;

__device__ __forceinline__ void gload16(const void* g, void* l) {
    __builtin_amdgcn_global_load_lds(
        (const __attribute__((address_space(1))) unsigned int*)g,
        (__attribute__((address_space(3))) unsigned int*)l, 16, 0, 0);
}

__device__ __forceinline__ unsigned pack2(float a, float b) {
    __hip_bfloat162 v = __float22bfloat162_rn(make_float2(a, b));
    return *reinterpret_cast<unsigned*>(&v);
}
__device__ __forceinline__ uint2 pack4(float4 f) {
    return make_uint2(pack2(f.x, f.y), pack2(f.z, f.w));
}
__device__ __forceinline__ float2 up2(unsigned u) {
    __hip_bfloat162 v = *reinterpret_cast<__hip_bfloat162*>(&u);
    return __bfloat1622float2(v);
}

// ---------------- prep_all: fp32 -> bf16 for everything the GEMM eats ----------------
// ws bf16 segment map (1M elems each):
//   segs 0..7  : wxi,wxf,wxc,wxo,whi,whf,whc,who
//   segs 8..9  : x (rows 0..1023, 1024..2047)
//   segs 10..17: hm[g][rowhalf] = h0 * maskHg   (hm_g contiguous as 2048x1024)
__global__ __launch_bounds__(256) void prep_all_k(
    const float* __restrict__ w0, const float* __restrict__ w1,
    const float* __restrict__ w2, const float* __restrict__ w3,
    const float* __restrict__ w4, const float* __restrict__ w5,
    const float* __restrict__ w6, const float* __restrict__ w7,
    const float* __restrict__ x, const float* __restrict__ h0,
    const float* __restrict__ mI, const float* __restrict__ mF,
    const float* __restrict__ mC, const float* __restrict__ mO,
    uint2* __restrict__ dst) {
    const int seg = blockIdx.y;
    const int i = blockIdx.x * 256 + threadIdx.x;   // float4 index within segment (262144)
    float4 f;
    if (seg < 10) {
        const float* base;
        switch (seg) {
            case 0: base = w0; break; case 1: base = w1; break;
            case 2: base = w2; break; case 3: base = w3; break;
            case 4: base = w4; break; case 5: base = w5; break;
            case 6: base = w6; break; case 7: base = w7; break;
            default: base = x + (size_t)(seg - 8) * WSEG; break;
        }
        f = ((const float4*)base)[i];
    } else {
        const int s = seg - 10;
        const int g = s >> 1, half = s & 1;
        const float* mp = (g == 0) ? mI : (g == 1) ? mF : (g == 2) ? mC : mO;
        float4 h = ((const float4*)(h0 + (size_t)half * WSEG))[i];
        float4 m = ((const float4*)(mp + (size_t)half * WSEG))[i];
        f = make_float4(h.x * m.x, h.y * m.y, h.z * m.z, h.w * m.w);
    }
    dst[(size_t)seg * (WSEG / 4) + i] = pack4(f);
}

// ---------------- gemm split-K: part[z=2g+half][b][n] = A_half[b,:]·B_gh[n,:]  (bf16 out) ----------------
// 1D grid of 1024, decoded z = id&7, by = (id>>3)&7, bx = id>>6 so that the
// round-robin block->XCD mapping (id%8) gives each XCD a single z (A 4MB + B 2MB
// working set vs 4MiB L2).  K=1024 per block, 128x128 tile, BK=64, 256 threads,
// 4x4 of 16x16x32 bf16 MFMA per wave.  LDS XOR-swizzled (R8: conflicts -> 0).
__global__ __launch_bounds__(256, 4) void gemm_split(
    const __hip_bfloat16* __restrict__ ws18,  // 18 x 1M bf16 per prep_all map
    __hip_bfloat16* __restrict__ part) {      // 8 x BH bf16
    const int id = blockIdx.x;
    const int z = id & 7;
    const int by = (id >> 3) & 7;
    const int bx = id >> 6;
    const int g = z >> 1, half = z & 1;
    const __hip_bfloat16* Ap = half ? (ws18 + (size_t)(10 + 2 * g) * WSEG)
                                    : (ws18 + (size_t)8 * WSEG);
    const __hip_bfloat16* Bp = half ? (ws18 + (size_t)(4 + g) * WSEG)
                                    : (ws18 + (size_t)g * WSEG);

    __shared__ __hip_bfloat16 As[128 * 64];
    __shared__ __hip_bfloat16 Bs[128 * 64];

    const int t = threadIdx.x;
    const int m0 = bx * 128;
    const int n0 = by * 128;
    const int wv = t >> 6, lane = t & 63;
    const int wm = (wv >> 1) * 64, wn = (wv & 1) * 64;
    const int quad = lane >> 4, lrow = lane & 15;

    float4v acc[4][4];
#pragma unroll
    for (int i = 0; i < 4; ++i)
#pragma unroll
        for (int j = 0; j < 4; ++j) acc[i][j] = (float4v){0.f, 0.f, 0.f, 0.f};

    const short8* As8 = (const short8*)As;
    const short8* Bs8 = (const short8*)Bs;

    for (int k0 = 0; k0 < 1024; k0 += 64) {
        // stage A-tile and B-tile (128 rows x 64 k): 1024 chunks of 16B per matrix,
        // 256 threads x 4.  chunk -> row = chunk>>3, SRC col-group = (chunk&7)^(row&7).
#pragma unroll
        for (int it = 0; it < 4; ++it) {
            int chunk = it * 256 + t;
            int row = chunk >> 3;
            int ccs = (chunk & 7) ^ (row & 7);
            gload16(Ap + (size_t)(m0 + row) * 1024 + k0 + ccs * 8,
                    (char*)As + chunk * 16);
            gload16(Bp + (size_t)(n0 + row) * 1024 + k0 + ccs * 8,
                    (char*)Bs + chunk * 16);
        }
        __syncthreads();

        // 2 k-steps of 32: logical col-chunk q = ks*4+quad lives at row*8 + (q^(row&7))
#pragma unroll
        for (int ks = 0; ks < 2; ++ks) {
            short8 af[4], bfr[4];
#pragma unroll
            for (int mt = 0; mt < 4; ++mt) {
                int r = wm + mt * 16 + lrow;
                af[mt] = As8[(r << 3) + ((ks * 4 + quad) ^ (r & 7))];
            }
#pragma unroll
            for (int nt = 0; nt < 4; ++nt) {
                int r = wn + nt * 16 + lrow;
                bfr[nt] = Bs8[(r << 3) + ((ks * 4 + quad) ^ (r & 7))];
            }
#pragma unroll
            for (int mt = 0; mt < 4; ++mt)
#pragma unroll
                for (int nt = 0; nt < 4; ++nt)
                    acc[mt][nt] = __builtin_amdgcn_mfma_f32_16x16x32_bf16(
                        af[mt], bfr[nt], acc[mt][nt], 0, 0, 0);
        }
        __syncthreads();
    }

    // epilogue: C/D layout col=lane&15, row=quad*4+r (m89/m91 verified); bf16 partial
    __hip_bfloat16* pz = part + (size_t)z * BH;
#pragma unroll
    for (int nt = 0; nt < 4; ++nt) {
        int col = n0 + wn + nt * 16 + lrow;
#pragma unroll
        for (int mt = 0; mt < 4; ++mt) {
#pragma unroll
            for (int r = 0; r < 4; ++r) {
                int row = m0 + wm + mt * 16 + quad * 4 + r;
                pz[(size_t)row * HDIM + col] = __float2bfloat16(acc[mt][nt][r]);
            }
        }
    }
}

// ---------------- combine: sum split-K partials + bias -> gates -> h1, c1 (fp32 out) ----------------
__global__ __launch_bounds__(256) void combine_k(
    const uint2* __restrict__ part,   // 8 x BH bf16, as uint2 = 4 elems
    const float* __restrict__ bi, const float* __restrict__ bff,
    const float* __restrict__ bc, const float* __restrict__ bo,
    const float* __restrict__ c0, const float* __restrict__ mC,
    float4* __restrict__ out) {
    const int i = blockIdx.x * 256 + threadIdx.x;   // 4-elem group index over BH/4
    const int h4 = (i * 4 & (HDIM - 1)) >> 2;       // float4 index into biases

    float gate[4][4];
#pragma unroll
    for (int g = 0; g < 4; ++g) {
        uint2 p0 = part[(size_t)(2 * g) * (BH / 4) + i];
        uint2 p1 = part[(size_t)(2 * g + 1) * (BH / 4) + i];
        float2 a0 = up2(p0.x), a1 = up2(p0.y);
        float2 b0 = up2(p1.x), b1 = up2(p1.y);
        gate[g][0] = a0.x + b0.x;
        gate[g][1] = a0.y + b0.y;
        gate[g][2] = a1.x + b1.x;
        gate[g][3] = a1.y + b1.y;
    }
    float4 vbi = ((const float4*)bi)[h4];
    float4 vbf = ((const float4*)bff)[h4];
    float4 vbc = ((const float4*)bc)[h4];
    float4 vbo = ((const float4*)bo)[h4];
    float4 vc0 = ((const float4*)c0)[i];
    float4 vmc = ((const float4*)mC)[i];
    const float* pbi = (const float*)&vbi;
    const float* pbf = (const float*)&vbf;
    const float* pbc = (const float*)&vbc;
    const float* pbo = (const float*)&vbo;
    const float* pc0 = (const float*)&vc0;
    const float* pmc = (const float*)&vmc;

    float h1[4], c1[4];
#pragma unroll
    for (int j = 0; j < 4; ++j) {
        float xi = gate[0][j] + pbi[j];
        float xf = gate[1][j] + pbf[j];
        float xc = gate[2][j] + pbc[j];
        float xo = gate[3][j] + pbo[j];
        float I = 1.f / (1.f + __expf(-xi));
        float F = 1.f / (1.f + __expf(-xf));
        float C = tanhf(xc) * pmc[j];
        float O = 1.f / (1.f + __expf(-xo));
        c1[j] = F * pc0[j] + I * C;
        h1[j] = O * tanhf(c1[j]);
    }
    out[i] = make_float4(h1[0], h1[1], h1[2], h1[3]);
    out[BH / 4 + i] = make_float4(c1[0], c1[1], c1[2], c1[3]);
}

extern "C" void kernel_launch(void* const* d_in, const int* in_sizes, int n_in,
                              void* d_out, int out_size, void* d_ws, size_t ws_size,
                              hipStream_t stream) {
    const float* x   = (const float*)d_in[0];
    const float* h0  = (const float*)d_in[1];
    const float* c0  = (const float*)d_in[2];
    const float* wxi = (const float*)d_in[3];
    const float* wxf = (const float*)d_in[4];
    const float* wxc = (const float*)d_in[5];
    const float* wxo = (const float*)d_in[6];
    const float* whi = (const float*)d_in[7];
    const float* whf = (const float*)d_in[8];
    const float* whc = (const float*)d_in[9];
    const float* who = (const float*)d_in[10];
    const float* bi  = (const float*)d_in[11];
    const float* bf  = (const float*)d_in[12];
    const float* bc  = (const float*)d_in[13];
    const float* bo  = (const float*)d_in[14];
    const float* mI  = (const float*)d_in[15];
    const float* mF  = (const float*)d_in[16];
    const float* mC  = (const float*)d_in[17];
    const float* mO  = (const float*)d_in[18];
    const float* mCell = (const float*)d_in[19];

    // ws layout: 18*1M bf16 = 36 MB | part: 8*BH bf16 = 32 MB
    __hip_bfloat16* ws18 = (__hip_bfloat16*)d_ws;
    __hip_bfloat16* part = ws18 + (size_t)18 * WSEG;

    prep_all_k<<<dim3(WSEG / 4 / 256, 18), dim3(256), 0, stream>>>(
        wxi, wxf, wxc, wxo, whi, whf, whc, who, x, h0, mI, mF, mC, mO,
        (uint2*)ws18);

    gemm_split<<<dim3(1024), dim3(256), 0, stream>>>(ws18, part);

    combine_k<<<dim3(BH / 4 / 256), dim3(256), 0, stream>>>(
        (const uint2*)part, bi, bf, bc, bo, c0, mCell, (float4*)d_out);
}